// Round 18
// baseline (306.314 us; speedup 1.0000x reference)
//
#include <hip/hip_runtime.h>
#include <hip/hip_bf16.h>
#include <stdint.h>

typedef __bf16 bf16x8 __attribute__((ext_vector_type(8)));
typedef float  f32x4  __attribute__((ext_vector_type(4)));

#define IN_DIM  4096
#define OUT_DIM 4096
#define M_DIM   8192

#define AS1 __attribute__((address_space(1)))
#define AS3 __attribute__((address_space(3)))

static __device__ __forceinline__ void gload_lds16(const void* g, void* l) {
  __builtin_amdgcn_global_load_lds((const AS1 void*)g, (AS3 void*)l, 16, 0, 0);
}
static __device__ __forceinline__ float bf2f(unsigned short u) {
  union { uint32_t i; float f; } c; c.i = (uint32_t)u << 16; return c.f;
}
static __device__ __forceinline__ unsigned short f2bf(float f) {
  __hip_bfloat16 h = __float2bfloat16(f); return *(const unsigned short*)&h;
}

// ------- Pass 1: decode + row FWHT(4096) + SU*1/64, fused x->bf16 convert -------
__global__ __launch_bounds__(256) void k_decode_fwht_row(
    const int* __restrict__ trellis, const float2* __restrict__ tlut,
    const float* __restrict__ SU, __hip_bfloat16* __restrict__ w,
    const float* __restrict__ x, __hip_bfloat16* __restrict__ xb)
{
  __shared__ float buf[4096];
  __shared__ int words[128];
  __shared__ float2 lut[1024];
  const int tid = threadIdx.x;
  const int r = blockIdx.x;

  float4 xv[8];
  #pragma unroll
  for (int rep = 0; rep < 4; ++rep) {
    size_t i = (((size_t)r * 4 + rep) * 256 + tid) * 8;
    xv[rep * 2]     = *(const float4*)(x + i);
    xv[rep * 2 + 1] = *(const float4*)(x + i + 4);
  }

  if (tid < 128) words[tid] = trellis[r * 128 + tid];
  for (int i = tid; i < 1024; i += 256) lut[i] = tlut[i];
  __syncthreads();

  float y[8][2];
  {
    const int t  = tid;
    const int wi = t >> 4;
    const int sh = 30 - 2 * (t & 15);
    const unsigned mask = (t < 4) ? ((1u << (2 * t + 2)) - 1u) : 1023u;
    #pragma unroll
    for (int s = 0; s < 8; ++s) {
      unsigned lo = (unsigned)words[s * 16 + wi];
      unsigned hi = wi ? (unsigned)words[s * 16 + wi - 1] : 0u;
      unsigned long long comb = ((unsigned long long)hi << 32) | (unsigned long long)lo;
      unsigned st = ((unsigned)(comb >> sh)) & mask;
      float2 v = lut[st];
      y[s][0] = v.x + v.y;   // bit 0 (h=1) in-register
      y[s][1] = v.x - v.y;
    }
  }
  #pragma unroll
  for (int st = 1; st < 8; st <<= 1) {
    #pragma unroll
    for (int s = 0; s < 8; ++s) {
      if (!(s & st)) {
        #pragma unroll
        for (int j = 0; j < 2; ++j) {
          float a = y[s][j], b = y[s | st][j];
          y[s][j]      = a + b;
          y[s | st][j] = a - b;
        }
      }
    }
  }
  #pragma unroll
  for (int s = 0; s < 8; ++s) {
    buf[s * 512 + 2 * tid]     = y[s][0];
    buf[s * 512 + 2 * tid + 1] = y[s][1];
  }
  __syncthreads();

  #pragma unroll
  for (int h = 2; h <= 128; h <<= 2) {
    #pragma unroll
    for (int p = 0; p < 4; ++p) {
      int q = p * 256 + tid;
      int i = ((q & ~(h - 1)) << 2) | (q & (h - 1));
      float p0 = buf[i], p1 = buf[i + h], p2 = buf[i + 2 * h], p3 = buf[i + 3 * h];
      float a = p0 + p1, b = p0 - p1, c2 = p2 + p3, d = p2 - p3;
      buf[i]         = a + c2;
      buf[i + h]     = b + d;
      buf[i + 2 * h] = a - c2;
      buf[i + 3 * h] = b - d;
    }
    __syncthreads();
  }

  for (int it2 = 0; it2 < 2; ++it2) {
    int c0 = (it2 * 256 + tid) * 8;
    union { unsigned short us[8]; uint4 v; } p;
    #pragma unroll
    for (int e = 0; e < 8; ++e)
      p.us[e] = f2bf(buf[c0 + e] * SU[c0 + e] * 0.015625f);
    *(uint4*)(w + (size_t)r * IN_DIM + c0) = p.v;
  }

  #pragma unroll
  for (int rep = 0; rep < 4; ++rep) {
    size_t i = (((size_t)r * 4 + rep) * 256 + tid) * 8;
    float4 v0 = xv[rep * 2], v1 = xv[rep * 2 + 1];
    union { __hip_bfloat16 h[8]; uint4 u; } p;
    p.h[0] = __float2bfloat16(v0.x); p.h[1] = __float2bfloat16(v0.y);
    p.h[2] = __float2bfloat16(v0.z); p.h[3] = __float2bfloat16(v0.w);
    p.h[4] = __float2bfloat16(v1.x); p.h[5] = __float2bfloat16(v1.y);
    p.h[6] = __float2bfloat16(v1.z); p.h[7] = __float2bfloat16(v1.w);
    *(uint4*)(xb + i) = p.u;
  }
}

// ------- Pass 2a: FWHT64 over row-index low 6 bits (3 radix-4 passes, in place) -------
__global__ __launch_bounds__(256) void k_fwht64_lo(__hip_bfloat16* __restrict__ w)
{
  __shared__ float tile[64][65];
  const int tid = threadIdx.x;
  const int rb = blockIdx.y, cb = blockIdx.x;

  for (int it = 0; it < 2; ++it) {
    int chunk = it * 256 + tid;
    int rr = chunk >> 3, jc = chunk & 7;
    uint4 v = *(const uint4*)(w + (size_t)(rb * 64 + rr) * IN_DIM + cb * 64 + jc * 8);
    const unsigned short* u = (const unsigned short*)&v;
    #pragma unroll
    for (int e = 0; e < 8; ++e) tile[rr][jc * 8 + e] = bf2f(u[e]);
  }
  __syncthreads();

  const int c = tid & 63, qf = tid >> 6;
  #pragma unroll
  for (int h = 1; h <= 16; h <<= 2) {
    #pragma unroll
    for (int u = 0; u < 4; ++u) {
      int q = qf * 4 + u;
      int i = ((q & ~(h - 1)) << 2) | (q & (h - 1));
      float p0 = tile[i][c], p1 = tile[i + h][c];
      float p2 = tile[i + 2 * h][c], p3 = tile[i + 3 * h][c];
      float a = p0 + p1, b = p0 - p1, cc = p2 + p3, d = p2 - p3;
      tile[i][c]         = a + cc;
      tile[i + h][c]     = b + d;
      tile[i + 2 * h][c] = a - cc;
      tile[i + 3 * h][c] = b - d;
    }
    __syncthreads();
  }

  for (int it = 0; it < 2; ++it) {
    int chunk = it * 256 + tid;
    int rr = chunk >> 3, jc = chunk & 7;
    union { unsigned short us[8]; uint4 v; } p;
    #pragma unroll
    for (int e = 0; e < 8; ++e) p.us[e] = f2bf(tile[rr][jc * 8 + e]);
    *(uint4*)(w + (size_t)(rb * 64 + rr) * IN_DIM + cb * 64 + jc * 8) = p.v;
  }
}

// ------- Pass 2b: FWHT64 over row-index high 6 bits + SV*1/64 (3 radix-4 passes) -------
__global__ __launch_bounds__(256) void k_fwht64_hi(__hip_bfloat16* __restrict__ w,
                                                   const float* __restrict__ SV)
{
  __shared__ float tile[64][65];
  const int tid = threadIdx.x;
  const int r0 = blockIdx.y, cb = blockIdx.x;

  for (int it = 0; it < 2; ++it) {
    int chunk = it * 256 + tid;
    int r1 = chunk >> 3, jc = chunk & 7;
    uint4 v = *(const uint4*)(w + (size_t)(r0 + 64 * r1) * IN_DIM + cb * 64 + jc * 8);
    const unsigned short* u = (const unsigned short*)&v;
    #pragma unroll
    for (int e = 0; e < 8; ++e) tile[r1][jc * 8 + e] = bf2f(u[e]);
  }
  __syncthreads();

  const int c = tid & 63, qf = tid >> 6;
  #pragma unroll
  for (int h = 1; h <= 16; h <<= 2) {
    #pragma unroll
    for (int u = 0; u < 4; ++u) {
      int q = qf * 4 + u;
      int i = ((q & ~(h - 1)) << 2) | (q & (h - 1));
      float p0 = tile[i][c], p1 = tile[i + h][c];
      float p2 = tile[i + 2 * h][c], p3 = tile[i + 3 * h][c];
      float a = p0 + p1, b = p0 - p1, cc = p2 + p3, d = p2 - p3;
      tile[i][c]         = a + cc;
      tile[i + h][c]     = b + d;
      tile[i + 2 * h][c] = a - cc;
      tile[i + 3 * h][c] = b - d;
    }
    __syncthreads();
  }

  for (int it = 0; it < 2; ++it) {
    int chunk = it * 256 + tid;
    int r1 = chunk >> 3, jc = chunk & 7;
    int row = r0 + 64 * r1;
    float sv = SV[row] * 0.015625f;
    union { unsigned short us[8]; uint4 v; } p;
    #pragma unroll
    for (int e = 0; e < 8; ++e) p.us[e] = f2bf(tile[r1][jc * 8 + e] * sv);
    *(uint4*)(w + (size_t)row * IN_DIM + cb * 64 + jc * 8) = p.v;
  }
}

// ==== GEMM: R17 structure, with B-fragment re-reads eliminated (24 reads/K-tile).
// b00a held live P8(prev)->P4 (Q00 and Q10 of buf0 tile); b01a held P4->P8 (buf1).
// P3/P7 are now read-free {stage + MFMA + VM4} phases. Read placements that remain
// are unchanged -> certification (VM4+BAR) identical to R17; regions' last LDS reads
// move EARLIER -> overwrite windows strictly safer.
#define GBM 256
#define GBN 256
#define GBK 64
#define NT  (IN_DIM / GBK)   // 64 K-tiles

__global__ __launch_bounds__(512, 1) void k_gemm256(
    const __hip_bfloat16* __restrict__ X,   // [8192][4096]
    const __hip_bfloat16* __restrict__ W,   // [4096][4096]
    float* __restrict__ out)                // [8192][4096]
{
  extern __shared__ __hip_bfloat16 smem[];  // 131072 B
  __hip_bfloat16* As = smem;                // [2][256*64]
  __hip_bfloat16* Bs = smem + 2 * 16384;

  const int tid  = threadIdx.x;
  const int lane = tid & 63;
  const int wave = tid >> 6;
  const int wm   = wave >> 2;       // 0..1 (M)
  const int wn   = wave & 3;        // 0..3 (N)
  const int lm   = lane & 15;
  const int lq   = lane >> 4;       // 0..3
  const int s_rw = tid >> 3;
  const int s_jj = tid & 7;

  // 8x8 chunk per XCD (grid 16x32)
  const int orig = blockIdx.y * gridDim.x + blockIdx.x;
  const int c8   = orig & 7;
  const int idx  = orig >> 3;
  const int bx   = (c8 & 1) * 8 + (idx & 7);
  const int by   = (c8 >> 1) * 8 + (idx >> 3);
  const int m0 = by * GBM, n0 = bx * GBN;

  f32x4 acc[8][4] = {};

#define STAGE_A(buf, u, kt) do {                                              \
    int row_ = (u) * 64 + s_rw;                                               \
    int js_  = s_jj ^ (row_ & 7);                                             \
    gload_lds16(X + (size_t)(m0 + row_) * IN_DIM + (kt) * GBK + js_ * 8,      \
                As + (buf) * 16384 + row_ * 64 + s_jj * 8);                   \
  } while (0)
#define STAGE_BE(buf, half, kt) do {                                          \
    int row_ = (half) * 128 + (s_rw & 31) + ((s_rw & 32) << 1);               \
    int js_  = s_jj ^ (row_ & 7);                                             \
    gload_lds16(W + (size_t)(n0 + row_) * IN_DIM + (kt) * GBK + js_ * 8,      \
                Bs + (buf) * 16384 + row_ * 64 + s_jj * 8);                   \
  } while (0)
#define STAGE_BL(buf, half, kt) do {                                          \
    int row_ = (half) * 128 + 32 + (s_rw & 31) + ((s_rw & 32) << 1);          \
    int js_  = s_jj ^ (row_ & 7);                                             \
    gload_lds16(W + (size_t)(n0 + row_) * IN_DIM + (kt) * GBK + js_ * 8,      \
                Bs + (buf) * 16384 + row_ * 64 + s_jj * 8);                   \
  } while (0)

#define RD_A_K(DST, QM, BUF, KK) do {                                         \
    const __hip_bfloat16* Ab_ = As + (BUF) * 16384;                           \
    _Pragma("unroll")                                                         \
    for (int mi2 = 0; mi2 < 4; ++mi2) {                                       \
      int r_ = wm * 128 + (QM) * 64 + mi2 * 16 + lm;                          \
      int q_ = (KK) * 4 + lq;                                                 \
      DST[mi2][KK] = *(const bf16x8*)(Ab_ + r_ * 64 + ((q_ ^ (r_ & 7)) << 3)); \
    }                                                                         \
  } while (0)
#define RD_A_TO(DST, QM, BUF) do {                                            \
    RD_A_K(DST, QM, BUF, 0); RD_A_K(DST, QM, BUF, 1);                         \
  } while (0)
#define RD_B_TO(DST, QN, BUF) do {                                            \
    const __hip_bfloat16* Bb_ = Bs + (BUF) * 16384;                           \
    _Pragma("unroll")                                                         \
    for (int ni2 = 0; ni2 < 2; ++ni2) {                                       \
      int r_ = wn * 64 + (QN) * 32 + ni2 * 16 + lm;                           \
      _Pragma("unroll")                                                       \
      for (int kk = 0; kk < 2; ++kk) {                                        \
        int q_ = kk * 4 + lq;                                                 \
        DST[ni2][kk] = *(const bf16x8*)(Bb_ + r_ * 64 + ((q_ ^ (r_ & 7)) << 3)); \
      }                                                                       \
    }                                                                         \
  } while (0)

#define FENCE asm volatile("" ::: "memory")
#define BAR do { FENCE; __builtin_amdgcn_s_barrier(); FENCE; } while (0)
#define VM4 do { asm volatile("s_waitcnt vmcnt(4)" ::: "memory"); } while (0)
#define MFMA_Q2(QM, QN, AF, BF) do {                                          \
    _Pragma("unroll")                                                         \
    for (int kk = 0; kk < 2; ++kk)                                            \
      _Pragma("unroll")                                                       \
      for (int mi2 = 0; mi2 < 4; ++mi2)                                       \
        _Pragma("unroll")                                                     \
        for (int ni2 = 0; ni2 < 2; ++ni2)                                     \
          acc[(QM) * 4 + mi2][(QN) * 2 + ni2] =                               \
              __builtin_amdgcn_mfma_f32_16x16x32_bf16(                        \
                  AF[mi2][kk], BF[ni2][kk],                                   \
                  acc[(QM) * 4 + mi2][(QN) * 2 + ni2], 0, 0, 0);              \
  } while (0)

  // loop-carried frags: aE0 (kk0 @P8, kk1 @P1) and b00a (@P8, used P1 AND P4)
  bf16x8 aE0[4][2], b00a[2][2];

  // --- prologue: buf0 <- t0 (8 stages), buf1 <- t1 partial {A02, BL, A13} ---
  STAGE_BE(0, 0, 0); STAGE_BE(0, 1, 0);
  STAGE_A (0, 0, 0); STAGE_A (0, 2, 0);
  STAGE_BL(0, 0, 0); STAGE_BL(0, 1, 0);
  STAGE_A (0, 1, 0); STAGE_A (0, 3, 0);
  STAGE_A (1, 0, 1); STAGE_A (1, 2, 1);
  STAGE_BL(1, 0, 1); STAGE_BL(1, 1, 1);
  STAGE_A (1, 1, 1); STAGE_A (1, 3, 1);
  asm volatile("s_waitcnt vmcnt(6)" ::: "memory");   // buf0-t0 landed
  BAR;
  RD_A_K(aE0, 0, 0, 0); RD_B_TO(b00a, 0, 0);

  for (int it = 0; it < NT / 2; ++it) {
    const int t1 = 2 * it + 1;
    const int t2 = (2 * it + 2 < NT) ? 2 * it + 2 : NT - 1;
    const int t3 = (2 * it + 3 < NT) ? 2 * it + 3 : NT - 1;

    bf16x8 aO0[4][2], aE1[4][2], aO1[4][2];
    bf16x8 b10[2][2], b01a[2][2], b11[2][2];

    // P1: MFMA(0,0,t0)=aE0,b00a ; RD b10 + aE0-kk1 (8) ; stage BE(buf1,t1)
    BAR;
    STAGE_BE(1, 0, t1); STAGE_BE(1, 1, t1);
    __builtin_amdgcn_s_setprio(1);
    RD_B_TO(b10, 1, 0);
    RD_A_K(aE0, 0, 0, 1);
    MFMA_Q2(0, 0, aE0, b00a);
    __builtin_amdgcn_s_setprio(0);

    // P2: MFMA(0,1,t0)=aE0,b10 ; RD aO0 (8) ; stage A02(buf0,t2)
    BAR;
    STAGE_A(0, 0, t2); STAGE_A(0, 2, t2);
    __builtin_amdgcn_s_setprio(1);
    RD_A_TO(aO0, 1, 0);
    MFMA_Q2(0, 1, aE0, b10);
    __builtin_amdgcn_s_setprio(0);

    // P3: MFMA(1,1,t0)=aO0,b10 ; no reads ; stage BL(buf0,t2) ; VM4
    BAR;
    STAGE_BL(0, 0, t2); STAGE_BL(0, 1, t2);
    __builtin_amdgcn_s_setprio(1);
    MFMA_Q2(1, 1, aO0, b10);
    __builtin_amdgcn_s_setprio(0);
    VM4;                                   // buf1-t1 fully landed

    // P4: MFMA(1,0,t0)=aO0,b00a [held] ; RD b01a + aE1-kk0 (8) ; stage A13(buf0,t2)
    BAR;
    STAGE_A(0, 1, t2); STAGE_A(0, 3, t2);
    __builtin_amdgcn_s_setprio(1);
    RD_B_TO(b01a, 0, 1);
    RD_A_K(aE1, 0, 1, 0);
    MFMA_Q2(1, 0, aO0, b00a);
    __builtin_amdgcn_s_setprio(0);

    // P5: MFMA(0,0,t1)=aE1,b01a ; RD b11 + aE1-kk1 (8) ; stage BE(buf0,t2)
    BAR;
    STAGE_BE(0, 0, t2); STAGE_BE(0, 1, t2);
    __builtin_amdgcn_s_setprio(1);
    RD_B_TO(b11, 1, 1);
    RD_A_K(aE1, 0, 1, 1);
    MFMA_Q2(0, 0, aE1, b01a);
    __builtin_amdgcn_s_setprio(0);

    // P6: MFMA(0,1,t1)=aE1,b11 ; RD aO1 (8) ; stage A02(buf1,t3)
    BAR;
    STAGE_A(1, 0, t3); STAGE_A(1, 2, t3);
    __builtin_amdgcn_s_setprio(1);
    RD_A_TO(aO1, 1, 1);
    MFMA_Q2(0, 1, aE1, b11);
    __builtin_amdgcn_s_setprio(0);

    // P7: MFMA(1,1,t1)=aO1,b11 ; no reads ; stage BL(buf1,t3) ; VM4
    BAR;
    STAGE_BL(1, 0, t3); STAGE_BL(1, 1, t3);
    __builtin_amdgcn_s_setprio(1);
    MFMA_Q2(1, 1, aO1, b11);
    __builtin_amdgcn_s_setprio(0);
    VM4;                                   // buf0-t2 fully landed

    // P8: MFMA(1,0,t1)=aO1,b01a [held] ; RD b00a + aE0-kk0 (8, buf0-t2) ; stage A13(buf1,t3)
    BAR;
    STAGE_A(1, 1, t3); STAGE_A(1, 3, t3);
    __builtin_amdgcn_s_setprio(1);
    RD_B_TO(b00a, 0, 0);
    RD_A_K(aE0, 0, 0, 0);
    MFMA_Q2(1, 0, aO1, b01a);
    __builtin_amdgcn_s_setprio(0);
  }

  asm volatile("s_waitcnt vmcnt(0)" ::: "memory");   // quiesce DMA before exit

  // --- epilogue: C/D layout col = lane&15, row = (lane>>4)*4 + reg ---
  #pragma unroll
  for (int mi = 0; mi < 8; ++mi) {
    #pragma unroll
    for (int ni = 0; ni < 4; ++ni) {
      int col   = n0 + wn * 64 + ni * 16 + lm;
      int rbase = m0 + wm * 128 + mi * 16 + lq * 4;
      #pragma unroll
      for (int rg = 0; rg < 4; ++rg) {
        out[(size_t)(rbase + rg) * OUT_DIM + col] = acc[mi][ni][rg];
      }
    }
  }
#undef MFMA_Q2
#undef VM4
#undef BAR
#undef FENCE
#undef RD_B_TO
#undef RD_A_TO
#undef RD_A_K
#undef STAGE_BL
#undef STAGE_BE
#undef STAGE_A
}

extern "C" void kernel_launch(void* const* d_in, const int* in_sizes, int n_in,
                              void* d_out, int out_size, void* d_ws, size_t ws_size,
                              hipStream_t stream) {
  (void)in_sizes; (void)n_in; (void)out_size; (void)ws_size;
  const float* x       = (const float*)d_in[0];
  const int*   trellis = (const int*)d_in[1];
  const float* tlut    = (const float*)d_in[2];
  const float* SU      = (const float*)d_in[3];
  const float* SV      = (const float*)d_in[4];
  float* out = (float*)d_out;

  __hip_bfloat16* Wd = (__hip_bfloat16*)d_ws;                                     // 32 MB
  __hip_bfloat16* Xb = (__hip_bfloat16*)((char*)d_ws + (size_t)32 * 1024 * 1024); // 64 MB

  k_decode_fwht_row<<<4096, 256, 0, stream>>>(trellis, (const float2*)tlut, SU, Wd, x, Xb);
  k_fwht64_lo<<<dim3(64, 64), 256, 0, stream>>>(Wd);
  k_fwht64_hi<<<dim3(64, 64), 256, 0, stream>>>(Wd, SV);

  hipFuncSetAttribute((const void*)k_gemm256,
                      hipFuncAttributeMaxDynamicSharedMemorySize, 131072);
  k_gemm256<<<dim3(IN_DIM / GBN, M_DIM / GBM), 512, 131072, stream>>>(Xb, Wd, out);
}

// Round 19
// 300.341 us; speedup vs baseline: 1.0199x; 1.0199x over previous
//
#include <hip/hip_runtime.h>
#include <hip/hip_bf16.h>
#include <stdint.h>

typedef __bf16 bf16x8 __attribute__((ext_vector_type(8)));
typedef float  f32x4  __attribute__((ext_vector_type(4)));

#define IN_DIM  4096
#define OUT_DIM 4096
#define M_DIM   8192

#define AS1 __attribute__((address_space(1)))
#define AS3 __attribute__((address_space(3)))

static __device__ __forceinline__ void gload_lds16(const void* g, void* l) {
  __builtin_amdgcn_global_load_lds((const AS1 void*)g, (AS3 void*)l, 16, 0, 0);
}
static __device__ __forceinline__ float bf2f(unsigned short u) {
  union { uint32_t i; float f; } c; c.i = (uint32_t)u << 16; return c.f;
}
static __device__ __forceinline__ unsigned short f2bf(float f) {
  __hip_bfloat16 h = __float2bfloat16(f); return *(const unsigned short*)&h;
}

// ------- Pass 1: decode + row FWHT(4096) + SU*1/64, fused x->bf16 convert -------
__global__ __launch_bounds__(256) void k_decode_fwht_row(
    const int* __restrict__ trellis, const float2* __restrict__ tlut,
    const float* __restrict__ SU, __hip_bfloat16* __restrict__ w,
    const float* __restrict__ x, __hip_bfloat16* __restrict__ xb)
{
  __shared__ float buf[4096];
  __shared__ int words[128];
  __shared__ float2 lut[1024];
  const int tid = threadIdx.x;
  const int r = blockIdx.x;

  float4 xv[8];
  #pragma unroll
  for (int rep = 0; rep < 4; ++rep) {
    size_t i = (((size_t)r * 4 + rep) * 256 + tid) * 8;
    xv[rep * 2]     = *(const float4*)(x + i);
    xv[rep * 2 + 1] = *(const float4*)(x + i + 4);
  }

  if (tid < 128) words[tid] = trellis[r * 128 + tid];
  for (int i = tid; i < 1024; i += 256) lut[i] = tlut[i];
  __syncthreads();

  float y[8][2];
  {
    const int t  = tid;
    const int wi = t >> 4;
    const int sh = 30 - 2 * (t & 15);
    const unsigned mask = (t < 4) ? ((1u << (2 * t + 2)) - 1u) : 1023u;
    #pragma unroll
    for (int s = 0; s < 8; ++s) {
      unsigned lo = (unsigned)words[s * 16 + wi];
      unsigned hi = wi ? (unsigned)words[s * 16 + wi - 1] : 0u;
      unsigned long long comb = ((unsigned long long)hi << 32) | (unsigned long long)lo;
      unsigned st = ((unsigned)(comb >> sh)) & mask;
      float2 v = lut[st];
      y[s][0] = v.x + v.y;   // bit 0 (h=1) in-register
      y[s][1] = v.x - v.y;
    }
  }
  #pragma unroll
  for (int st = 1; st < 8; st <<= 1) {
    #pragma unroll
    for (int s = 0; s < 8; ++s) {
      if (!(s & st)) {
        #pragma unroll
        for (int j = 0; j < 2; ++j) {
          float a = y[s][j], b = y[s | st][j];
          y[s][j]      = a + b;
          y[s | st][j] = a - b;
        }
      }
    }
  }
  #pragma unroll
  for (int s = 0; s < 8; ++s) {
    buf[s * 512 + 2 * tid]     = y[s][0];
    buf[s * 512 + 2 * tid + 1] = y[s][1];
  }
  __syncthreads();

  #pragma unroll
  for (int h = 2; h <= 128; h <<= 2) {
    #pragma unroll
    for (int p = 0; p < 4; ++p) {
      int q = p * 256 + tid;
      int i = ((q & ~(h - 1)) << 2) | (q & (h - 1));
      float p0 = buf[i], p1 = buf[i + h], p2 = buf[i + 2 * h], p3 = buf[i + 3 * h];
      float a = p0 + p1, b = p0 - p1, c2 = p2 + p3, d = p2 - p3;
      buf[i]         = a + c2;
      buf[i + h]     = b + d;
      buf[i + 2 * h] = a - c2;
      buf[i + 3 * h] = b - d;
    }
    __syncthreads();
  }

  for (int it2 = 0; it2 < 2; ++it2) {
    int c0 = (it2 * 256 + tid) * 8;
    union { unsigned short us[8]; uint4 v; } p;
    #pragma unroll
    for (int e = 0; e < 8; ++e)
      p.us[e] = f2bf(buf[c0 + e] * SU[c0 + e] * 0.015625f);
    *(uint4*)(w + (size_t)r * IN_DIM + c0) = p.v;
  }

  #pragma unroll
  for (int rep = 0; rep < 4; ++rep) {
    size_t i = (((size_t)r * 4 + rep) * 256 + tid) * 8;
    float4 v0 = xv[rep * 2], v1 = xv[rep * 2 + 1];
    union { __hip_bfloat16 h[8]; uint4 u; } p;
    p.h[0] = __float2bfloat16(v0.x); p.h[1] = __float2bfloat16(v0.y);
    p.h[2] = __float2bfloat16(v0.z); p.h[3] = __float2bfloat16(v0.w);
    p.h[4] = __float2bfloat16(v1.x); p.h[5] = __float2bfloat16(v1.y);
    p.h[6] = __float2bfloat16(v1.z); p.h[7] = __float2bfloat16(v1.w);
    *(uint4*)(xb + i) = p.u;
  }
}

// ------- Pass 2a: FWHT64 over row-index low 6 bits (3 radix-4 passes, in place) -------
__global__ __launch_bounds__(256) void k_fwht64_lo(__hip_bfloat16* __restrict__ w)
{
  __shared__ float tile[64][65];
  const int tid = threadIdx.x;
  const int rb = blockIdx.y, cb = blockIdx.x;

  for (int it = 0; it < 2; ++it) {
    int chunk = it * 256 + tid;
    int rr = chunk >> 3, jc = chunk & 7;
    uint4 v = *(const uint4*)(w + (size_t)(rb * 64 + rr) * IN_DIM + cb * 64 + jc * 8);
    const unsigned short* u = (const unsigned short*)&v;
    #pragma unroll
    for (int e = 0; e < 8; ++e) tile[rr][jc * 8 + e] = bf2f(u[e]);
  }
  __syncthreads();

  const int c = tid & 63, qf = tid >> 6;
  #pragma unroll
  for (int h = 1; h <= 16; h <<= 2) {
    #pragma unroll
    for (int u = 0; u < 4; ++u) {
      int q = qf * 4 + u;
      int i = ((q & ~(h - 1)) << 2) | (q & (h - 1));
      float p0 = tile[i][c], p1 = tile[i + h][c];
      float p2 = tile[i + 2 * h][c], p3 = tile[i + 3 * h][c];
      float a = p0 + p1, b = p0 - p1, cc = p2 + p3, d = p2 - p3;
      tile[i][c]         = a + cc;
      tile[i + h][c]     = b + d;
      tile[i + 2 * h][c] = a - cc;
      tile[i + 3 * h][c] = b - d;
    }
    __syncthreads();
  }

  for (int it = 0; it < 2; ++it) {
    int chunk = it * 256 + tid;
    int rr = chunk >> 3, jc = chunk & 7;
    union { unsigned short us[8]; uint4 v; } p;
    #pragma unroll
    for (int e = 0; e < 8; ++e) p.us[e] = f2bf(tile[rr][jc * 8 + e]);
    *(uint4*)(w + (size_t)(rb * 64 + rr) * IN_DIM + cb * 64 + jc * 8) = p.v;
  }
}

// ------- Pass 2b: FWHT64 over row-index high 6 bits + SV*1/64 (3 radix-4 passes) -------
__global__ __launch_bounds__(256) void k_fwht64_hi(__hip_bfloat16* __restrict__ w,
                                                   const float* __restrict__ SV)
{
  __shared__ float tile[64][65];
  const int tid = threadIdx.x;
  const int r0 = blockIdx.y, cb = blockIdx.x;

  for (int it = 0; it < 2; ++it) {
    int chunk = it * 256 + tid;
    int r1 = chunk >> 3, jc = chunk & 7;
    uint4 v = *(const uint4*)(w + (size_t)(r0 + 64 * r1) * IN_DIM + cb * 64 + jc * 8);
    const unsigned short* u = (const unsigned short*)&v;
    #pragma unroll
    for (int e = 0; e < 8; ++e) tile[r1][jc * 8 + e] = bf2f(u[e]);
  }
  __syncthreads();

  const int c = tid & 63, qf = tid >> 6;
  #pragma unroll
  for (int h = 1; h <= 16; h <<= 2) {
    #pragma unroll
    for (int u = 0; u < 4; ++u) {
      int q = qf * 4 + u;
      int i = ((q & ~(h - 1)) << 2) | (q & (h - 1));
      float p0 = tile[i][c], p1 = tile[i + h][c];
      float p2 = tile[i + 2 * h][c], p3 = tile[i + 3 * h][c];
      float a = p0 + p1, b = p0 - p1, cc = p2 + p3, d = p2 - p3;
      tile[i][c]         = a + cc;
      tile[i + h][c]     = b + d;
      tile[i + 2 * h][c] = a - cc;
      tile[i + 3 * h][c] = b - d;
    }
    __syncthreads();
  }

  for (int it = 0; it < 2; ++it) {
    int chunk = it * 256 + tid;
    int r1 = chunk >> 3, jc = chunk & 7;
    int row = r0 + 64 * r1;
    float sv = SV[row] * 0.015625f;
    union { unsigned short us[8]; uint4 v; } p;
    #pragma unroll
    for (int e = 0; e < 8; ++e) p.us[e] = f2bf(tile[r1][jc * 8 + e] * sv);
    *(uint4*)(w + (size_t)row * IN_DIM + cb * 64 + jc * 8) = p.v;
  }
}

// ==== GEMM: R17 exact (measured 225.0 us, MfmaUtil 57.1, 0 conflicts) ================
// 16x16x32, 8-phase counted VM4, 8x8 XCD chunk, burst-balanced reads (max 8/phase),
// kk-outer MFMA so in-phase kk=1 reads hide under kk=0 MFMAs.
#define GBM 256
#define GBN 256
#define GBK 64
#define NT  (IN_DIM / GBK)   // 64 K-tiles

__global__ __launch_bounds__(512, 1) void k_gemm256(
    const __hip_bfloat16* __restrict__ X,   // [8192][4096]
    const __hip_bfloat16* __restrict__ W,   // [4096][4096]
    float* __restrict__ out)                // [8192][4096]
{
  extern __shared__ __hip_bfloat16 smem[];  // 131072 B
  __hip_bfloat16* As = smem;                // [2][256*64]
  __hip_bfloat16* Bs = smem + 2 * 16384;

  const int tid  = threadIdx.x;
  const int lane = tid & 63;
  const int wave = tid >> 6;
  const int wm   = wave >> 2;       // 0..1 (M)
  const int wn   = wave & 3;        // 0..3 (N)
  const int lm   = lane & 15;
  const int lq   = lane >> 4;       // 0..3
  const int s_rw = tid >> 3;
  const int s_jj = tid & 7;

  // 8x8 chunk per XCD (grid 16x32)
  const int orig = blockIdx.y * gridDim.x + blockIdx.x;
  const int c8   = orig & 7;
  const int idx  = orig >> 3;
  const int bx   = (c8 & 1) * 8 + (idx & 7);
  const int by   = (c8 >> 1) * 8 + (idx >> 3);
  const int m0 = by * GBM, n0 = bx * GBN;

  f32x4 acc[8][4] = {};

#define STAGE_A(buf, u, kt) do {                                              \
    int row_ = (u) * 64 + s_rw;                                               \
    int js_  = s_jj ^ (row_ & 7);                                             \
    gload_lds16(X + (size_t)(m0 + row_) * IN_DIM + (kt) * GBK + js_ * 8,      \
                As + (buf) * 16384 + row_ * 64 + s_jj * 8);                   \
  } while (0)
#define STAGE_BE(buf, half, kt) do {                                          \
    int row_ = (half) * 128 + (s_rw & 31) + ((s_rw & 32) << 1);               \
    int js_  = s_jj ^ (row_ & 7);                                             \
    gload_lds16(W + (size_t)(n0 + row_) * IN_DIM + (kt) * GBK + js_ * 8,      \
                Bs + (buf) * 16384 + row_ * 64 + s_jj * 8);                   \
  } while (0)
#define STAGE_BL(buf, half, kt) do {                                          \
    int row_ = (half) * 128 + 32 + (s_rw & 31) + ((s_rw & 32) << 1);          \
    int js_  = s_jj ^ (row_ & 7);                                             \
    gload_lds16(W + (size_t)(n0 + row_) * IN_DIM + (kt) * GBK + js_ * 8,      \
                Bs + (buf) * 16384 + row_ * 64 + s_jj * 8);                   \
  } while (0)

#define RD_A_K(DST, QM, BUF, KK) do {                                         \
    const __hip_bfloat16* Ab_ = As + (BUF) * 16384;                           \
    _Pragma("unroll")                                                         \
    for (int mi2 = 0; mi2 < 4; ++mi2) {                                       \
      int r_ = wm * 128 + (QM) * 64 + mi2 * 16 + lm;                          \
      int q_ = (KK) * 4 + lq;                                                 \
      DST[mi2][KK] = *(const bf16x8*)(Ab_ + r_ * 64 + ((q_ ^ (r_ & 7)) << 3)); \
    }                                                                         \
  } while (0)
#define RD_A_TO(DST, QM, BUF) do {                                            \
    RD_A_K(DST, QM, BUF, 0); RD_A_K(DST, QM, BUF, 1);                         \
  } while (0)
#define RD_B_TO(DST, QN, BUF) do {                                            \
    const __hip_bfloat16* Bb_ = Bs + (BUF) * 16384;                           \
    _Pragma("unroll")                                                         \
    for (int ni2 = 0; ni2 < 2; ++ni2) {                                       \
      int r_ = wn * 64 + (QN) * 32 + ni2 * 16 + lm;                           \
      _Pragma("unroll")                                                       \
      for (int kk = 0; kk < 2; ++kk) {                                        \
        int q_ = kk * 4 + lq;                                                 \
        DST[ni2][kk] = *(const bf16x8*)(Bb_ + r_ * 64 + ((q_ ^ (r_ & 7)) << 3)); \
      }                                                                       \
    }                                                                         \
  } while (0)

#define FENCE asm volatile("" ::: "memory")
#define BAR do { FENCE; __builtin_amdgcn_s_barrier(); FENCE; } while (0)
#define VM4 do { asm volatile("s_waitcnt vmcnt(4)" ::: "memory"); } while (0)
#define MFMA_Q2(QM, QN, AF, BF) do {                                          \
    _Pragma("unroll")                                                         \
    for (int kk = 0; kk < 2; ++kk)                                            \
      _Pragma("unroll")                                                       \
      for (int mi2 = 0; mi2 < 4; ++mi2)                                       \
        _Pragma("unroll")                                                     \
        for (int ni2 = 0; ni2 < 2; ++ni2)                                     \
          acc[(QM) * 4 + mi2][(QN) * 2 + ni2] =                               \
              __builtin_amdgcn_mfma_f32_16x16x32_bf16(                        \
                  AF[mi2][kk], BF[ni2][kk],                                   \
                  acc[(QM) * 4 + mi2][(QN) * 2 + ni2], 0, 0, 0);              \
  } while (0)

  // loop-carried frags (aE0 kk0 + b00a written P8, aE0 kk1 written P1)
  bf16x8 aE0[4][2], b00a[2][2];

  // --- prologue: buf0 <- t0 (8 stages), buf1 <- t1 partial {A02, BL, A13} ---
  STAGE_BE(0, 0, 0); STAGE_BE(0, 1, 0);
  STAGE_A (0, 0, 0); STAGE_A (0, 2, 0);
  STAGE_BL(0, 0, 0); STAGE_BL(0, 1, 0);
  STAGE_A (0, 1, 0); STAGE_A (0, 3, 0);
  STAGE_A (1, 0, 1); STAGE_A (1, 2, 1);
  STAGE_BL(1, 0, 1); STAGE_BL(1, 1, 1);
  STAGE_A (1, 1, 1); STAGE_A (1, 3, 1);
  asm volatile("s_waitcnt vmcnt(6)" ::: "memory");   // buf0-t0 landed
  BAR;
  RD_A_K(aE0, 0, 0, 0); RD_B_TO(b00a, 0, 0);

  for (int it = 0; it < NT / 2; ++it) {
    const int t1 = 2 * it + 1;
    const int t2 = (2 * it + 2 < NT) ? 2 * it + 2 : NT - 1;
    const int t3 = (2 * it + 3 < NT) ? 2 * it + 3 : NT - 1;

    bf16x8 aO0[4][2], aE1[4][2], aO1[4][2];
    bf16x8 b10[2][2], b00b[2][2], b01a[2][2], b11[2][2], b01b[2][2];

    // P1: MFMA(0,0,t0)=aE0,b00a ; RD b10 + aE0-kk1 (8) ; stage BE(buf1,t1)
    BAR;
    STAGE_BE(1, 0, t1); STAGE_BE(1, 1, t1);
    __builtin_amdgcn_s_setprio(1);
    RD_B_TO(b10, 1, 0);
    RD_A_K(aE0, 0, 0, 1);
    MFMA_Q2(0, 0, aE0, b00a);
    __builtin_amdgcn_s_setprio(0);

    // P2: MFMA(0,1,t0)=aE0,b10 ; RD aO0 (8) ; stage A02(buf0,t2)
    BAR;
    STAGE_A(0, 0, t2); STAGE_A(0, 2, t2);
    __builtin_amdgcn_s_setprio(1);
    RD_A_TO(aO0, 1, 0);
    MFMA_Q2(0, 1, aE0, b10);
    __builtin_amdgcn_s_setprio(0);

    // P3: MFMA(1,1,t0)=aO0,b10 ; RD b00b (4) ; stage BL(buf0,t2) ; VM4
    BAR;
    STAGE_BL(0, 0, t2); STAGE_BL(0, 1, t2);
    __builtin_amdgcn_s_setprio(1);
    RD_B_TO(b00b, 0, 0);
    MFMA_Q2(1, 1, aO0, b10);
    __builtin_amdgcn_s_setprio(0);
    VM4;                                   // buf1-t1 fully landed

    // P4: MFMA(1,0,t0)=aO0,b00b ; RD b01a + aE1-kk0 (8) ; stage A13(buf0,t2)
    BAR;
    STAGE_A(0, 1, t2); STAGE_A(0, 3, t2);
    __builtin_amdgcn_s_setprio(1);
    RD_B_TO(b01a, 0, 1);
    RD_A_K(aE1, 0, 1, 0);
    MFMA_Q2(1, 0, aO0, b00b);
    __builtin_amdgcn_s_setprio(0);

    // P5: MFMA(0,0,t1)=aE1,b01a ; RD b11 + aE1-kk1 (8) ; stage BE(buf0,t2)
    BAR;
    STAGE_BE(0, 0, t2); STAGE_BE(0, 1, t2);
    __builtin_amdgcn_s_setprio(1);
    RD_B_TO(b11, 1, 1);
    RD_A_K(aE1, 0, 1, 1);
    MFMA_Q2(0, 0, aE1, b01a);
    __builtin_amdgcn_s_setprio(0);

    // P6: MFMA(0,1,t1)=aE1,b11 ; RD aO1 (8) ; stage A02(buf1,t3)
    BAR;
    STAGE_A(1, 0, t3); STAGE_A(1, 2, t3);
    __builtin_amdgcn_s_setprio(1);
    RD_A_TO(aO1, 1, 1);
    MFMA_Q2(0, 1, aE1, b11);
    __builtin_amdgcn_s_setprio(0);

    // P7: MFMA(1,1,t1)=aO1,b11 ; RD b01b (4) ; stage BL(buf1,t3) ; VM4
    BAR;
    STAGE_BL(1, 0, t3); STAGE_BL(1, 1, t3);
    __builtin_amdgcn_s_setprio(1);
    RD_B_TO(b01b, 0, 1);
    MFMA_Q2(1, 1, aO1, b11);
    __builtin_amdgcn_s_setprio(0);
    VM4;                                   // buf0-t2 fully landed

    // P8: MFMA(1,0,t1)=aO1,b01b ; RD b00a + aE0-kk0 (8, buf0-t2) ; stage A13(buf1,t3)
    BAR;
    STAGE_A(1, 1, t3); STAGE_A(1, 3, t3);
    __builtin_amdgcn_s_setprio(1);
    RD_B_TO(b00a, 0, 0);
    RD_A_K(aE0, 0, 0, 0);
    MFMA_Q2(1, 0, aO1, b01b);
    __builtin_amdgcn_s_setprio(0);
  }

  asm volatile("s_waitcnt vmcnt(0)" ::: "memory");   // quiesce DMA before exit

  // --- epilogue: C/D layout col = lane&15, row = (lane>>4)*4 + reg ---
  #pragma unroll
  for (int mi = 0; mi < 8; ++mi) {
    #pragma unroll
    for (int ni = 0; ni < 4; ++ni) {
      int col   = n0 + wn * 64 + ni * 16 + lm;
      int rbase = m0 + wm * 128 + mi * 16 + lq * 4;
      #pragma unroll
      for (int rg = 0; rg < 4; ++rg) {
        out[(size_t)(rbase + rg) * OUT_DIM + col] = acc[mi][ni][rg];
      }
    }
  }
#undef MFMA_Q2
#undef VM4
#undef BAR
#undef FENCE
#undef RD_B_TO
#undef RD_A_TO
#undef RD_A_K
#undef STAGE_BL
#undef STAGE_BE
#undef STAGE_A
}

extern "C" void kernel_launch(void* const* d_in, const int* in_sizes, int n_in,
                              void* d_out, int out_size, void* d_ws, size_t ws_size,
                              hipStream_t stream) {
  (void)in_sizes; (void)n_in; (void)out_size; (void)ws_size;
  const float* x       = (const float*)d_in[0];
  const int*   trellis = (const int*)d_in[1];
  const float* tlut    = (const float*)d_in[2];
  const float* SU      = (const float*)d_in[3];
  const float* SV      = (const float*)d_in[4];
  float* out = (float*)d_out;

  __hip_bfloat16* Wd = (__hip_bfloat16*)d_ws;                                     // 32 MB
  __hip_bfloat16* Xb = (__hip_bfloat16*)((char*)d_ws + (size_t)32 * 1024 * 1024); // 64 MB

  k_decode_fwht_row<<<4096, 256, 0, stream>>>(trellis, (const float2*)tlut, SU, Wd, x, Xb);
  k_fwht64_lo<<<dim3(64, 64), 256, 0, stream>>>(Wd);
  k_fwht64_hi<<<dim3(64, 64), 256, 0, stream>>>(Wd, SV);

  hipFuncSetAttribute((const void*)k_gemm256,
                      hipFuncAttributeMaxDynamicSharedMemorySize, 131072);
  k_gemm256<<<dim3(IN_DIM / GBN, M_DIM / GBM), 512, 131072, stream>>>(Xb, Wd, out);
}